// Round 10
// baseline (473.855 us; speedup 1.0000x reference)
//
#include <hip/hip_runtime.h>

typedef __attribute__((ext_vector_type(8))) short bf16x8;
typedef __attribute__((ext_vector_type(4))) float f32x4;

#define HID 50
#define TSTEPS 512
#define LOG2E 1.4426950408889634f

static __device__ __forceinline__ short f2bf(float f) {
    unsigned u = __builtin_bit_cast(unsigned, f);
    u = (u + 0x7fffu + ((u >> 16) & 1u)) >> 16;   // RNE
    return (short)u;
}

static __device__ __forceinline__ float fexp2(float x) {
#if __has_builtin(__builtin_amdgcn_exp2f)
    return __builtin_amdgcn_exp2f(x);
#else
    return exp2f(x);
#endif
}
static __device__ __forceinline__ float frcp(float x) {
#if __has_builtin(__builtin_amdgcn_rcpf)
    return __builtin_amdgcn_rcpf(x);
#else
    return 1.0f / x;
#endif
}
static __device__ __forceinline__ float sigm(float x) {
    return frcp(1.0f + fexp2(-LOG2E * x));
}
static __device__ __forceinline__ float tanh_(float x) {
    return 1.0f - 2.0f * frcp(1.0f + fexp2(2.0f * LOG2E * x));
}

// LDS-write-only barrier: drain lgkmcnt (ds_writes) but leave global x-prefetch
// loads in flight. sched_barrier(0) per rule 18.
static __device__ __forceinline__ void lds_barrier() {
    asm volatile("s_waitcnt lgkmcnt(0)" ::: "memory");
    __builtin_amdgcn_sched_barrier(0);
    __builtin_amdgcn_s_barrier();
}

// R8: 4 waves, 16 rows/block split into TWO phase-shifted 8-row LSTM instances.
// r-split: instance ALPHA owns C-rows lq*4+{0,1} (batch rows with (b&3)<2),
// BETA owns lq*4+{2,3}. Each instance has its own double-buffered 16x64 bf16
// swizzled LDS tile (rows of the other instance stay zero; their C output is
// discarded). Per half-step phase:
//   PHASE_A: ds_read h_beta tile | act(alpha from prev MFMA) | write h_alpha |
//            MFMA(beta) | barrier
//   PHASE_B: symmetric alpha<->beta.
// The ~300 cyc of one instance's activation issue hides the other instance's
// ds_read + MFMA latency IN-STREAM (R7 showed cross-wave hiding fails under
// a lockstep barrier). MFMA count doubles (matrix pipe was 9.6% busy - free).
//
// Gate pre-activation per instance is ONE K=64 MFMA pair:
//   A row b = [ h[b][0..49] | x[b][t][0..3] | 1.0 | 0.. ]
//   B col j = [ W_hh[g][j][:] | W_ih[g][j][:] | bias_g[j] | 0.. ] (VGPR-resident)
__global__ __launch_bounds__(256) void lstm_fused(
    const float* __restrict__ seq,
    const float* __restrict__ W_ih,
    const float* __restrict__ W_hh,
    const float* __restrict__ b_ih,
    const float* __restrict__ b_hh,
    const float* __restrict__ W_out,
    const float* __restrict__ b_out,
    float* __restrict__ out)
{
    // tiles (2KB each): alpha[0]=0, alpha[1]=2048, beta[0]=4096, beta[1]=6144
    __shared__ __align__(16) short h_lds[4 * 16 * 64];
    __shared__ float h32[16][51];

    const int tid = threadIdx.x;
    const int l   = tid & 63;
    const int wv  = tid >> 6;          // wave = j-slice 0..3
    const int l15 = l & 15;
    const int lq  = l >> 4;            // 0..3
    const int jl  = wv * 16 + l15;     // padded hidden col 0..63
    const bool jv = (jl < HID);
    const int rowbase = blockIdx.x << 4;
    const int swz = (l15 & 7) << 4;    // A-read swizzle (row = l15)

    for (int i = tid; i < 4 * 16 * 64; i += 256) h_lds[i] = 0;

    // ---- B fragments: [W_hh^T | W_ih^T | bias], bf16, VGPR-resident all 512 steps.
    bf16x8 Bf[4][2];
#pragma unroll
    for (int g = 0; g < 4; ++g)
#pragma unroll
        for (int kk = 0; kk < 2; ++kk) {
            bf16x8 v;
#pragma unroll
            for (int e = 0; e < 8; ++e) {
                int k = kk * 32 + lq * 8 + e;
                float val = 0.0f;
                if (jv) {
                    if (k < HID)            val = W_hh[(g * HID + jl) * HID + k];
                    else if (k < HID + 4)   val = W_ih[(g * HID + jl) * 4 + (k - HID)];
                    else if (k == HID + 4)  val = b_ih[g * HID + jl] + b_hh[g * HID + jl];
                }
                v[e] = f2bf(val);
            }
            Bf[g][kk] = v;
        }

    // ---- x prefetch: lq==2 lanes feed x (k=48..55 A-slice). Two rolling regs;
    // x(t) is injected twice (once per instance, adjacent phases).
    const char* xp = (const char*)seq + (size_t)(rowbase + l15) * TSTEPS * 16;
    float4 xE = make_float4(0.f, 0.f, 0.f, 0.f);   // even-t x
    float4 xO = make_float4(0.f, 0.f, 0.f, 0.f);   // odd-t x
    if (lq == 2) {
        xE = *(const float4*)(xp);
        xO = *(const float4*)(xp + 16);
    }

    float cA0 = 0.f, cA1 = 0.f, hA0 = 0.f, hA1 = 0.f;   // alpha state (rows lq*4+0,1)
    float cB0 = 0.f, cB1 = 0.f, hB0 = 0.f, hB1 = 0.f;   // beta  state (rows lq*4+2,3)

    // ---- loop-invariant LDS addresses (tile offsets fold into ds imm)
    const char* rd0 = (const char*)h_lds + l15 * 128 + ((lq * 16) ^ swz);
    const char* rd1 = (const char*)h_lds + l15 * 128 + ((64 + lq * 16) ^ swz);
    const int rA0 = lq * 4, rA1 = rA0 + 1, rB0 = rA0 + 2, rB1 = rA0 + 3;
    char* wbA0 = (char*)h_lds + rA0 * 128 + ((2 * jl) ^ ((rA0 & 7) << 4));
    char* wbA1 = (char*)h_lds + rA1 * 128 + ((2 * jl) ^ ((rA1 & 7) << 4));
    char* wbB0 = (char*)h_lds + rB0 * 128 + ((2 * jl) ^ ((rB0 & 7) << 4));
    char* wbB1 = (char*)h_lds + rB1 * 128 + ((2 * jl) ^ ((rB1 & 7) << 4));

    __syncthreads();   // tiles zeroed

    // ---- prologue: z_alpha(0) = x(0)*Wih + bias (h=0 tile -> zero A-frags)
    f32x4 aA0 = {0.f,0.f,0.f,0.f}, aA1 = {0.f,0.f,0.f,0.f};
    f32x4 aA2 = {0.f,0.f,0.f,0.f}, aA3 = {0.f,0.f,0.f,0.f};
    f32x4 aB0 = {0.f,0.f,0.f,0.f}, aB1 = {0.f,0.f,0.f,0.f};
    f32x4 aB2 = {0.f,0.f,0.f,0.f}, aB3 = {0.f,0.f,0.f,0.f};
    {
        bf16x8 a0 = {0,0,0,0,0,0,0,0};
        bf16x8 a1 = {0,0,0,0,0,0,0,0};
        if (lq == 2) {
            a1[2] = f2bf(xE.x); a1[3] = f2bf(xE.y);
            a1[4] = f2bf(xE.z); a1[5] = f2bf(xE.w);
            a1[6] = (short)0x3f80;
        }
        aA0 = __builtin_amdgcn_mfma_f32_16x16x32_bf16(a0, Bf[0][0], aA0, 0, 0, 0);
        aA1 = __builtin_amdgcn_mfma_f32_16x16x32_bf16(a0, Bf[1][0], aA1, 0, 0, 0);
        aA2 = __builtin_amdgcn_mfma_f32_16x16x32_bf16(a0, Bf[2][0], aA2, 0, 0, 0);
        aA3 = __builtin_amdgcn_mfma_f32_16x16x32_bf16(a0, Bf[3][0], aA3, 0, 0, 0);
        aA0 = __builtin_amdgcn_mfma_f32_16x16x32_bf16(a1, Bf[0][1], aA0, 0, 0, 0);
        aA1 = __builtin_amdgcn_mfma_f32_16x16x32_bf16(a1, Bf[1][1], aA1, 0, 0, 0);
        aA2 = __builtin_amdgcn_mfma_f32_16x16x32_bf16(a1, Bf[2][1], aA2, 0, 0, 0);
        aA3 = __builtin_amdgcn_mfma_f32_16x16x32_bf16(a1, Bf[3][1], aA3, 0, 0, 0);
    }

    // PHASE_A(TA_WR = alpha tile to write, TB_RD = beta tile to read, XREG = x(t)):
    //   act(alpha) from aA*, write h_alpha, MFMA(beta) -> aB*, barrier.
#define PHASE_A(TA_WR, TB_RD, XREG)                                                            \
    {                                                                                          \
        bf16x8 a0 = *(const bf16x8*)(rd0 + (TB_RD));                                           \
        bf16x8 a1 = *(const bf16x8*)(rd1 + (TB_RD));                                           \
        if (lq == 2) {                                                                         \
            a1[2] = f2bf(XREG.x); a1[3] = f2bf(XREG.y);                                        \
            a1[4] = f2bf(XREG.z); a1[5] = f2bf(XREG.w);                                        \
            a1[6] = (short)0x3f80;                                                             \
        }                                                                                      \
        {                                                                                      \
            float iv = sigm(aA0[0]), fv = sigm(aA1[0]), gv = tanh_(aA2[0]), ov = sigm(aA3[0]); \
            cA0 = fv * cA0 + iv * gv;  hA0 = ov * tanh_(cA0);                                  \
        }                                                                                      \
        {                                                                                      \
            float iv = sigm(aA0[1]), fv = sigm(aA1[1]), gv = tanh_(aA2[1]), ov = sigm(aA3[1]); \
            cA1 = fv * cA1 + iv * gv;  hA1 = ov * tanh_(cA1);                                  \
        }                                                                                      \
        if (jv) {                                                                              \
            *(short*)(wbA0 + (TA_WR)) = f2bf(hA0);                                             \
            *(short*)(wbA1 + (TA_WR)) = f2bf(hA1);                                             \
        }                                                                                      \
        aB0 = (f32x4){0.f,0.f,0.f,0.f}; aB1 = (f32x4){0.f,0.f,0.f,0.f};                        \
        aB2 = (f32x4){0.f,0.f,0.f,0.f}; aB3 = (f32x4){0.f,0.f,0.f,0.f};                        \
        aB0 = __builtin_amdgcn_mfma_f32_16x16x32_bf16(a0, Bf[0][0], aB0, 0, 0, 0);             \
        aB1 = __builtin_amdgcn_mfma_f32_16x16x32_bf16(a0, Bf[1][0], aB1, 0, 0, 0);             \
        aB2 = __builtin_amdgcn_mfma_f32_16x16x32_bf16(a0, Bf[2][0], aB2, 0, 0, 0);             \
        aB3 = __builtin_amdgcn_mfma_f32_16x16x32_bf16(a0, Bf[3][0], aB3, 0, 0, 0);             \
        aB0 = __builtin_amdgcn_mfma_f32_16x16x32_bf16(a1, Bf[0][1], aB0, 0, 0, 0);             \
        aB1 = __builtin_amdgcn_mfma_f32_16x16x32_bf16(a1, Bf[1][1], aB1, 0, 0, 0);             \
        aB2 = __builtin_amdgcn_mfma_f32_16x16x32_bf16(a1, Bf[2][1], aB2, 0, 0, 0);             \
        aB3 = __builtin_amdgcn_mfma_f32_16x16x32_bf16(a1, Bf[3][1], aB3, 0, 0, 0);             \
        lds_barrier();                                                                         \
    }

    // PHASE_B(TB_WR = beta tile to write, TA_RD = alpha tile to read, XREG = x(t+1))
#define PHASE_B(TB_WR, TA_RD, XREG)                                                            \
    {                                                                                          \
        bf16x8 a0 = *(const bf16x8*)(rd0 + (TA_RD));                                           \
        bf16x8 a1 = *(const bf16x8*)(rd1 + (TA_RD));                                           \
        if (lq == 2) {                                                                         \
            a1[2] = f2bf(XREG.x); a1[3] = f2bf(XREG.y);                                        \
            a1[4] = f2bf(XREG.z); a1[5] = f2bf(XREG.w);                                        \
            a1[6] = (short)0x3f80;                                                             \
        }                                                                                      \
        {                                                                                      \
            float iv = sigm(aB0[2]), fv = sigm(aB1[2]), gv = tanh_(aB2[2]), ov = sigm(aB3[2]); \
            cB0 = fv * cB0 + iv * gv;  hB0 = ov * tanh_(cB0);                                  \
        }                                                                                      \
        {                                                                                      \
            float iv = sigm(aB0[3]), fv = sigm(aB1[3]), gv = tanh_(aB2[3]), ov = sigm(aB3[3]); \
            cB1 = fv * cB1 + iv * gv;  hB1 = ov * tanh_(cB1);                                  \
        }                                                                                      \
        if (jv) {                                                                              \
            *(short*)(wbB0 + (TB_WR)) = f2bf(hB0);                                             \
            *(short*)(wbB1 + (TB_WR)) = f2bf(hB1);                                             \
        }                                                                                      \
        aA0 = (f32x4){0.f,0.f,0.f,0.f}; aA1 = (f32x4){0.f,0.f,0.f,0.f};                        \
        aA2 = (f32x4){0.f,0.f,0.f,0.f}; aA3 = (f32x4){0.f,0.f,0.f,0.f};                        \
        aA0 = __builtin_amdgcn_mfma_f32_16x16x32_bf16(a0, Bf[0][0], aA0, 0, 0, 0);             \
        aA1 = __builtin_amdgcn_mfma_f32_16x16x32_bf16(a0, Bf[1][0], aA1, 0, 0, 0);             \
        aA2 = __builtin_amdgcn_mfma_f32_16x16x32_bf16(a0, Bf[2][0], aA2, 0, 0, 0);             \
        aA3 = __builtin_amdgcn_mfma_f32_16x16x32_bf16(a0, Bf[3][0], aA3, 0, 0, 0);             \
        aA0 = __builtin_amdgcn_mfma_f32_16x16x32_bf16(a1, Bf[0][1], aA0, 0, 0, 0);             \
        aA1 = __builtin_amdgcn_mfma_f32_16x16x32_bf16(a1, Bf[1][1], aA1, 0, 0, 0);             \
        aA2 = __builtin_amdgcn_mfma_f32_16x16x32_bf16(a1, Bf[2][1], aA2, 0, 0, 0);             \
        aA3 = __builtin_amdgcn_mfma_f32_16x16x32_bf16(a1, Bf[3][1], aA3, 0, 0, 0);             \
        lds_barrier();                                                                         \
    }

    // Unrolled 2 timesteps (4 phases) so tile parities are compile-time.
    // iter t   (p=0): A: write ta[1](2048), read tb[0](4096); B: write tb[1](6144), read ta[1](2048)
    // iter t+1 (p=1): A: write ta[0](0),    read tb[1](6144); B: write tb[0](4096), read ta[0](0)
    for (int t = 0; t < TSTEPS; t += 2) {
        PHASE_A(2048, 4096, xE);                                   // inject x(t)
        if (t + 2 < TSTEPS && lq == 2)
            xE = *(const float4*)(xp + (t + 2) * 16);
        PHASE_B(6144, 2048, xO);                                   // inject x(t+1)
        PHASE_A(0, 6144, xO);                                      // inject x(t+1)
        if (t + 3 < TSTEPS && lq == 2)
            xO = *(const float4*)(xp + (t + 3) * 16);
        PHASE_B(4096, 0, xE);                                      // inject x(t+2)
    }
#undef PHASE_A
#undef PHASE_B

    // ---- epilogue: out[b] = h_last[b,:] @ W_out + b_out
    if (jv) {
        h32[rA0][jl] = hA0;
        h32[rA1][jl] = hA1;
        h32[rB0][jl] = hB0;
        h32[rB1][jl] = hB1;
    }
    __syncthreads();
    if (tid < 16) {
        float s = b_out[0];
        for (int j = 0; j < HID; ++j) s += h32[tid][j] * W_out[j];
        out[rowbase + tid] = s;
    }
}

extern "C" void kernel_launch(void* const* d_in, const int* in_sizes, int n_in,
                              void* d_out, int out_size, void* d_ws, size_t ws_size,
                              hipStream_t stream) {
    const float* seq   = (const float*)d_in[0];
    const float* W_ih  = (const float*)d_in[1];
    const float* W_hh  = (const float*)d_in[2];
    const float* b_ih  = (const float*)d_in[3];
    const float* b_hh  = (const float*)d_in[4];
    const float* W_out = (const float*)d_in[5];
    const float* b_out = (const float*)d_in[6];
    float* out = (float*)d_out;

    const int B = in_sizes[0] / (TSTEPS * 4);   // 4096
    lstm_fused<<<dim3(B / 16), dim3(256), 0, stream>>>(
        seq, W_ih, W_hh, b_ih, b_hh, W_out, b_out, out);
}

// Round 11
// 427.383 us; speedup vs baseline: 1.1087x; 1.1087x over previous
//
#include <hip/hip_runtime.h>

typedef __attribute__((ext_vector_type(8))) short bf16x8;
typedef __attribute__((ext_vector_type(4))) float f32x4;

#define HID 50
#define TSTEPS 512
#define LOG2E 1.4426950408889634f

static __device__ __forceinline__ short f2bf(float f) {
    unsigned u = __builtin_bit_cast(unsigned, f);
    u = (u + 0x7fffu + ((u >> 16) & 1u)) >> 16;   // RNE
    return (short)u;
}

static __device__ __forceinline__ float fexp2(float x) {
#if __has_builtin(__builtin_amdgcn_exp2f)
    return __builtin_amdgcn_exp2f(x);
#else
    return exp2f(x);
#endif
}
static __device__ __forceinline__ float frcp(float x) {
#if __has_builtin(__builtin_amdgcn_rcpf)
    return __builtin_amdgcn_rcpf(x);
#else
    return 1.0f / x;
#endif
}
static __device__ __forceinline__ float sigm(float x) {
    return frcp(1.0f + fexp2(-LOG2E * x));
}
static __device__ __forceinline__ float tanh_(float x) {
    return 1.0f - 2.0f * frcp(1.0f + fexp2(2.0f * LOG2E * x));
}

// lgkm-only barrier (measured neutral vs __syncthreads, kept: leaves x loads in flight)
static __device__ __forceinline__ void lds_barrier() {
    asm volatile("s_waitcnt lgkmcnt(0)" ::: "memory");
    __builtin_amdgcn_sched_barrier(0);
    __builtin_amdgcn_s_barrier();
}

// R11: M=8 rows/block, grid=512 -> TWO independent blocks per CU (independent
// barriers interleave the ~600cyc/phase serial overhead that R7/R8 proved
// cannot be hidden within one barrier group). To make 2 waves/SIMD profitable
// the per-wave issue must drop below ~687cyc (=R6 1373/2): the activation is
// repacked IN-WAVE (LDS scratch, no barrier) from the MFMA C-layout (128
// quadruples in lanes 0..31) to full density (2 quadruples on each of 64
// lanes) -> act issue halves. Per-element arithmetic identical to R6.
//
// MFMA structure as R6: wave = j-slice of 16 (4 gate-tiles), A-tile 16x64
// (rows 8..15 permanently zero), gate pre-activation via one K=64 MFMA pair:
//   A row b = [ h[b][0..49] | x[b][t][0..3] | 1.0 | 0.. ]
//   B col j = [ W_hh[g][j][:] | W_ih[g][j][:] | bias_g[j] | 0.. ] (VGPR-resident)
//
// Scratch layout (per wave, 2KB): (row 0..7, jj 0..15) -> 16B quad at
//   byte = row*256 + SLOT*16,  SLOT = jj ^ (row&1) ^ ((row>>2)<<1)
// XORs chosen so the 64-lane paired b128 reads cover all 32 banks evenly
// (8 start-groups x 8 lanes). Row-parity XOR is absorbed by per-lane-constant
// j-labels (jE at +0, jO at +16); c-state follows the labels, so no runtime
// selects except 2 cndmask at the h-pack.
__global__ __launch_bounds__(256) void lstm_fused(
    const float* __restrict__ seq,
    const float* __restrict__ W_ih,
    const float* __restrict__ W_hh,
    const float* __restrict__ b_ih,
    const float* __restrict__ b_hh,
    const float* __restrict__ W_out,
    const float* __restrict__ b_out,
    float* __restrict__ out)
{
    __shared__ __align__(16) short h_lds[2 * 16 * 64];  // 2 dbuf A-tiles, 2KB each
    __shared__ __align__(16) float scr[4 * 512];        // per-wave 2KB act scratch
    __shared__ float h32[8][51];                        // final h staging

    const int tid = threadIdx.x;
    const int l   = tid & 63;
    const int wv  = tid >> 6;          // wave = j-slice 0..3
    const int l15 = l & 15;
    const int lq  = l >> 4;            // 0..3
    const int jl  = wv * 16 + l15;     // padded hidden col 0..63
    const bool jv = (jl < HID);
    const int rowbase = blockIdx.x << 3;   // 8 rows/block
    const int swz = (l15 & 7) << 4;    // A-read swizzle (row = l15)

    for (int i = tid; i < 2 * 16 * 64; i += 256) h_lds[i] = 0;

    // ---- B fragments: [W_hh^T | W_ih^T | bias], bf16, VGPR-resident (as R6)
    bf16x8 Bf[4][2];
#pragma unroll
    for (int g = 0; g < 4; ++g)
#pragma unroll
        for (int kk = 0; kk < 2; ++kk) {
            bf16x8 v;
#pragma unroll
            for (int e = 0; e < 8; ++e) {
                int k = kk * 32 + lq * 8 + e;
                float val = 0.0f;
                if (jv) {
                    if (k < HID)            val = W_hh[(g * HID + jl) * HID + k];
                    else if (k < HID + 4)   val = W_ih[(g * HID + jl) * 4 + (k - HID)];
                    else if (k == HID + 4)  val = b_ih[g * HID + jl] + b_hh[g * HID + jl];
                }
                v[e] = f2bf(val);
            }
            Bf[g][kk] = v;
        }

    // ---- x prefetch: lq==2 lanes, rows l15<8 only (M=8). Distance-2.
    const char* xp = (const char*)seq + (size_t)(rowbase + l15) * TSTEPS * 16;
    const bool xl = (lq == 2) && (l15 < 8);
    float4 xE = make_float4(0.f, 0.f, 0.f, 0.f);
    float4 xO = make_float4(0.f, 0.f, 0.f, 0.f);
    if (xl) {
        xE = *(const float4*)(xp);
        xO = *(const float4*)(xp + 16);
    }

    // ---- MFMA-side loop-invariant LDS addresses (A-frag reads, as R6)
    const char* rdA = (const char*)h_lds + l15 * 128 + ((lq * 16) ^ swz);
    const char* rdB = (const char*)h_lds + l15 * 128 + ((64 + lq * 16) ^ swz);

    // ---- scratch write ptrs (lanes lq<2 own MFMA rows lq*4+r):
    //   byte(r) = (lq*4+r)*256 + ((l15 ^ (r&1) ^ (lq<<1)))*16
    char* const swb = (char*)(scr + wv * 512);
    char* const pw0 = swb + lq * 1024 + ((l15 ^ (lq << 1)) << 4);           // r=0 (+512: r=2)
    char* const pw1 = swb + lq * 1024 + 256 + ((l15 ^ 1 ^ (lq << 1)) << 4); // r=1 (+512: r=3)

    // ---- act-side per-lane constants
    const int arow = l >> 3;            // act row 0..7
    const int jj0  = (l & 7) << 1;      // even jj base
    const bool rodd = (arow & 1) != 0;
    const char* const pr = swb + arow * 256 + ((jj0 ^ ((arow >> 2) << 1)) << 4);
    const int jE = wv * 16 + jj0 + (rodd ? 1 : 0);       // label of quad at pr+0
    const int jO = wv * 16 + jj0 + (rodd ? 0 : 1);       // label of quad at pr+16
    // h word covers (arow, j=wv*16+jj0) low half and +1 high half:
    char* const hw = (char*)h_lds + arow * 128 + (((wv * 16 + jj0) * 2) ^ ((arow & 7) << 4));
    const bool hok = (wv * 16 + jj0) <= 48;              // both j's < 50

    float cE = 0.f, cO = 0.f, hE = 0.f, hO = 0.f;

    __syncthreads();   // A-tiles zeroed

    // One step: A-read(prev h) -> inject x -> 8 MFMA -> scratch repack (in-wave)
    // -> act 2 quads/lane -> pack h word -> write A[next] -> barrier.
#define STEP(TT, XREG, RDOFF, WROFF)                                                           \
    {                                                                                          \
        bf16x8 a0 = *(const bf16x8*)(rdA + (RDOFF));                                           \
        bf16x8 a1 = *(const bf16x8*)(rdB + (RDOFF));                                           \
        if (lq == 2) {                                                                         \
            a1[2] = f2bf(XREG.x); a1[3] = f2bf(XREG.y);                                        \
            a1[4] = f2bf(XREG.z); a1[5] = f2bf(XREG.w);                                        \
            a1[6] = (short)0x3f80;  /* 1.0 -> bias row */                                      \
        }                                                                                      \
        if ((TT) + 2 < TSTEPS && xl)                                                           \
            XREG = *(const float4*)(xp + ((TT) + 2) * 16);                                     \
        f32x4 ac0 = {0.f,0.f,0.f,0.f}, ac1 = {0.f,0.f,0.f,0.f};                                \
        f32x4 ac2 = {0.f,0.f,0.f,0.f}, ac3 = {0.f,0.f,0.f,0.f};                                \
        ac0 = __builtin_amdgcn_mfma_f32_16x16x32_bf16(a0, Bf[0][0], ac0, 0, 0, 0);             \
        ac1 = __builtin_amdgcn_mfma_f32_16x16x32_bf16(a0, Bf[1][0], ac1, 0, 0, 0);             \
        ac2 = __builtin_amdgcn_mfma_f32_16x16x32_bf16(a0, Bf[2][0], ac2, 0, 0, 0);             \
        ac3 = __builtin_amdgcn_mfma_f32_16x16x32_bf16(a0, Bf[3][0], ac3, 0, 0, 0);             \
        ac0 = __builtin_amdgcn_mfma_f32_16x16x32_bf16(a1, Bf[0][1], ac0, 0, 0, 0);             \
        ac1 = __builtin_amdgcn_mfma_f32_16x16x32_bf16(a1, Bf[1][1], ac1, 0, 0, 0);             \
        ac2 = __builtin_amdgcn_mfma_f32_16x16x32_bf16(a1, Bf[2][1], ac2, 0, 0, 0);             \
        ac3 = __builtin_amdgcn_mfma_f32_16x16x32_bf16(a1, Bf[3][1], ac3, 0, 0, 0);             \
        if (lq < 2) {                                                                          \
            f32x4 t0 = {ac0[0], ac1[0], ac2[0], ac3[0]};                                       \
            f32x4 t1 = {ac0[1], ac1[1], ac2[1], ac3[1]};                                       \
            f32x4 t2 = {ac0[2], ac1[2], ac2[2], ac3[2]};                                       \
            f32x4 t3 = {ac0[3], ac1[3], ac2[3], ac3[3]};                                       \
            *(f32x4*)(pw0)       = t0;                                                         \
            *(f32x4*)(pw1)       = t1;                                                         \
            *(f32x4*)(pw0 + 512) = t2;                                                         \
            *(f32x4*)(pw1 + 512) = t3;                                                         \
        }                                                                                      \
        f32x4 qE = *(const f32x4*)(pr);         /* same-wave RAW: compiler lgkm-orders */      \
        f32x4 qO = *(const f32x4*)(pr + 16);                                                   \
        {                                                                                      \
            float iv = sigm(qE[0]), fv = sigm(qE[1]), gv = tanh_(qE[2]), ov = sigm(qE[3]);     \
            cE = fv * cE + iv * gv;  hE = ov * tanh_(cE);                                      \
        }                                                                                      \
        {                                                                                      \
            float iv = sigm(qO[0]), fv = sigm(qO[1]), gv = tanh_(qO[2]), ov = sigm(qO[3]);     \
            cO = fv * cO + iv * gv;  hO = ov * tanh_(cO);                                      \
        }                                                                                      \
        if (hok) {                                                                             \
            unsigned uE = (unsigned short)f2bf(hE);                                            \
            unsigned uO = (unsigned short)f2bf(hO);                                            \
            unsigned lo = rodd ? uO : uE;                                                      \
            unsigned hi = rodd ? uE : uO;                                                      \
            *(unsigned*)(hw + (WROFF)) = (hi << 16) | lo;                                      \
        }                                                                                      \
        lds_barrier();                                                                         \
    }

    for (int t = 0; t < TSTEPS; t += 2) {
        STEP(t,     xE, 0,    2048);
        STEP(t + 1, xO, 2048, 0);
    }
#undef STEP

    // ---- epilogue: out[b] = h_last[b,:] @ W_out + b_out
    if (jE < HID) h32[arow][jE] = hE;
    if (jO < HID) h32[arow][jO] = hO;
    __syncthreads();
    if (tid < 8) {
        float s = b_out[0];
        for (int j = 0; j < HID; ++j) s += h32[tid][j] * W_out[j];
        out[rowbase + tid] = s;
    }
}

extern "C" void kernel_launch(void* const* d_in, const int* in_sizes, int n_in,
                              void* d_out, int out_size, void* d_ws, size_t ws_size,
                              hipStream_t stream) {
    const float* seq   = (const float*)d_in[0];
    const float* W_ih  = (const float*)d_in[1];
    const float* W_hh  = (const float*)d_in[2];
    const float* b_ih  = (const float*)d_in[3];
    const float* b_hh  = (const float*)d_in[4];
    const float* W_out = (const float*)d_in[5];
    const float* b_out = (const float*)d_in[6];
    float* out = (float*)d_out;

    const int B = in_sizes[0] / (TSTEPS * 4);   // 4096
    lstm_fused<<<dim3(B / 8), dim3(256), 0, stream>>>(
        seq, W_ih, W_hh, b_ih, b_hh, W_out, b_out, out);
}

// Round 13
// 349.061 us; speedup vs baseline: 1.3575x; 1.2244x over previous
//
#include <hip/hip_runtime.h>

typedef __attribute__((ext_vector_type(8))) short bf16x8;
typedef __attribute__((ext_vector_type(4))) float f32x4;

#define HID 50
#define TSTEPS 512
#define LOG2E 1.4426950408889634f

static __device__ __forceinline__ short f2bf(float f) {
    unsigned u = __builtin_bit_cast(unsigned, f);
    u = (u + 0x7fffu + ((u >> 16) & 1u)) >> 16;   // RNE
    return (short)u;
}

static __device__ __forceinline__ float fexp2(float x) {
#if __has_builtin(__builtin_amdgcn_exp2f)
    return __builtin_amdgcn_exp2f(x);
#else
    return exp2f(x);
#endif
}
static __device__ __forceinline__ float frcp(float x) {
#if __has_builtin(__builtin_amdgcn_rcpf)
    return __builtin_amdgcn_rcpf(x);
#else
    return 1.0f / x;
#endif
}
static __device__ __forceinline__ float sigm(float x) {
    return frcp(1.0f + fexp2(-LOG2E * x));
}
static __device__ __forceinline__ float tanh_(float x) {
    return 1.0f - 2.0f * frcp(1.0f + fexp2(2.0f * LOG2E * x));
}

// lgkm-only barrier (measured equal to __syncthreads; keeps x loads in flight)
static __device__ __forceinline__ void lds_barrier() {
    asm volatile("s_waitcnt lgkmcnt(0)" ::: "memory");
    __builtin_amdgcn_sched_barrier(0);
    __builtin_amdgcn_s_barrier();
}

// R12 = R6 structure (best measured: 293us; 4 waves, 1/SIMD, j-split, 1 barrier/step)
// with the intra-step critical path re-scheduled, math bitwise-identical:
//  - 4 a0-partial MFMAs first (no x-inject dependency), then per-gate a1-chain
//    immediately followed by that gate's activations (trans overlaps MFMA pipe).
//  - c and tanh(c) computed before gate-o's act (hides acO latency).
//  - h-writes unguarded (cols 50..54 always overwritten by inject; 55..63 hit
//    zero B-rows) and issued per-r as soon as ready.
__global__ __launch_bounds__(256) void lstm_fused(
    const float* __restrict__ seq,
    const float* __restrict__ W_ih,
    const float* __restrict__ W_hh,
    const float* __restrict__ b_ih,
    const float* __restrict__ b_hh,
    const float* __restrict__ W_out,
    const float* __restrict__ b_out,
    float* __restrict__ out)
{
    __shared__ __align__(16) short h_lds[2 * 16 * 64];  // bf16 bits, dbuf, XOR-swizzled rows of 128B
    __shared__ float h32[16][51];                       // final h staging

    const int tid = threadIdx.x;
    const int l   = tid & 63;
    const int wv  = tid >> 6;          // wave = j-slice 0..3
    const int l15 = l & 15;
    const int lq  = l >> 4;            // 0..3
    const int jl  = wv * 16 + l15;     // padded hidden col 0..63
    const bool jv = (jl < HID);
    const int rowbase = blockIdx.x << 4;
    const int swz = (l15 & 7) << 4;    // A-read swizzle (row = l15)

    for (int i = tid; i < 2 * 16 * 64; i += 256) h_lds[i] = 0;

    // ---- B fragments: [W_hh^T | W_ih^T | bias], bf16, VGPR-resident all 512 steps.
    bf16x8 Bf[4][2];
#pragma unroll
    for (int g = 0; g < 4; ++g)
#pragma unroll
        for (int kk = 0; kk < 2; ++kk) {
            bf16x8 v;
#pragma unroll
            for (int e = 0; e < 8; ++e) {
                int k = kk * 32 + lq * 8 + e;
                float val = 0.0f;
                if (jv) {
                    if (k < HID)            val = W_hh[(g * HID + jl) * HID + k];
                    else if (k < HID + 4)   val = W_ih[(g * HID + jl) * 4 + (k - HID)];
                    else if (k == HID + 4)  val = b_ih[g * HID + jl] + b_hh[g * HID + jl];
                }
                v[e] = f2bf(val);
            }
            Bf[g][kk] = v;
        }

    // ---- x prefetch: lq==2 lanes feed x (k=48..55 A-slice). Distance-2.
    const char* xp = (const char*)seq + (size_t)(rowbase + l15) * TSTEPS * 16;
    float4 xE = make_float4(0.f, 0.f, 0.f, 0.f);
    float4 xO = make_float4(0.f, 0.f, 0.f, 0.f);
    if (lq == 2) {
        xE = *(const float4*)(xp);
        xO = *(const float4*)(xp + 16);
    }

    float c[4] = {0.f, 0.f, 0.f, 0.f};
    float h[4] = {0.f, 0.f, 0.f, 0.f};

    // ---- loop-invariant LDS addresses (dbuf offsets fold into ds imm)
    const char* rdA = (const char*)h_lds + l15 * 128 + ((lq * 16) ^ swz);
    const char* rdB = (const char*)h_lds + l15 * 128 + ((64 + lq * 16) ^ swz);
    char* wb[4];
#pragma unroll
    for (int r = 0; r < 4; ++r) {
        int row = lq * 4 + r;
        wb[r] = (char*)h_lds + row * 128 + ((2 * jl) ^ ((row & 7) << 4));
    }

    __syncthreads();   // h_lds zeroed

    // One step, path-scheduled:
    //   reads -> inject -> prefetch -> 4 a0-partials ->
    //   {acI -> iv} {acF -> fv} {acG -> gv} -> c, tanh(c) -> {acO -> ov} -> h, write
#define STEP(TT, XREG, RDOFF, WROFF)                                                           \
    {                                                                                          \
        bf16x8 a0 = *(const bf16x8*)(rdA + (RDOFF));                                           \
        bf16x8 a1 = *(const bf16x8*)(rdB + (RDOFF));                                           \
        if (lq == 2) {                                                                         \
            a1[2] = f2bf(XREG.x); a1[3] = f2bf(XREG.y);                                        \
            a1[4] = f2bf(XREG.z); a1[5] = f2bf(XREG.w);                                        \
            a1[6] = (short)0x3f80;  /* 1.0 -> bias row */                                      \
        }                                                                                      \
        if ((TT) + 2 < TSTEPS && lq == 2)                                                      \
            XREG = *(const float4*)(xp + ((TT) + 2) * 16);                                     \
        f32x4 z = {0.f, 0.f, 0.f, 0.f};                                                        \
        f32x4 p0 = __builtin_amdgcn_mfma_f32_16x16x32_bf16(a0, Bf[0][0], z, 0, 0, 0);          \
        f32x4 p1 = __builtin_amdgcn_mfma_f32_16x16x32_bf16(a0, Bf[1][0], z, 0, 0, 0);          \
        f32x4 p2 = __builtin_amdgcn_mfma_f32_16x16x32_bf16(a0, Bf[2][0], z, 0, 0, 0);          \
        f32x4 p3 = __builtin_amdgcn_mfma_f32_16x16x32_bf16(a0, Bf[3][0], z, 0, 0, 0);          \
        f32x4 acI = __builtin_amdgcn_mfma_f32_16x16x32_bf16(a1, Bf[0][1], p0, 0, 0, 0);        \
        float iv0 = sigm(acI[0]), iv1 = sigm(acI[1]), iv2 = sigm(acI[2]), iv3 = sigm(acI[3]);  \
        f32x4 acF = __builtin_amdgcn_mfma_f32_16x16x32_bf16(a1, Bf[1][1], p1, 0, 0, 0);        \
        float fv0 = sigm(acF[0]), fv1 = sigm(acF[1]), fv2 = sigm(acF[2]), fv3 = sigm(acF[3]);  \
        f32x4 acG = __builtin_amdgcn_mfma_f32_16x16x32_bf16(a1, Bf[2][1], p2, 0, 0, 0);        \
        float gv0 = tanh_(acG[0]), gv1 = tanh_(acG[1]);                                        \
        float gv2 = tanh_(acG[2]), gv3 = tanh_(acG[3]);                                        \
        c[0] = fv0 * c[0] + iv0 * gv0;                                                         \
        c[1] = fv1 * c[1] + iv1 * gv1;                                                         \
        c[2] = fv2 * c[2] + iv2 * gv2;                                                         \
        c[3] = fv3 * c[3] + iv3 * gv3;                                                         \
        float tc0 = tanh_(c[0]), tc1 = tanh_(c[1]);                                            \
        float tc2 = tanh_(c[2]), tc3 = tanh_(c[3]);                                            \
        f32x4 acO = __builtin_amdgcn_mfma_f32_16x16x32_bf16(a1, Bf[3][1], p3, 0, 0, 0);        \
        float ov0 = sigm(acO[0]), ov1 = sigm(acO[1]), ov2 = sigm(acO[2]), ov3 = sigm(acO[3]);  \
        h[0] = ov0 * tc0;  *(short*)(wb[0] + (WROFF)) = f2bf(h[0]);                            \
        h[1] = ov1 * tc1;  *(short*)(wb[1] + (WROFF)) = f2bf(h[1]);                            \
        h[2] = ov2 * tc2;  *(short*)(wb[2] + (WROFF)) = f2bf(h[2]);                            \
        h[3] = ov3 * tc3;  *(short*)(wb[3] + (WROFF)) = f2bf(h[3]);                            \
        lds_barrier();                                                                         \
    }

    for (int t = 0; t < TSTEPS; t += 2) {
        STEP(t,     xE, 0,    2048);
        STEP(t + 1, xO, 2048, 0);
    }
#undef STEP

    // ---- epilogue: out[b] = h_last[b,:] @ W_out + b_out (fp32 h from regs)
    if (jv) {
#pragma unroll
        for (int r = 0; r < 4; ++r) h32[lq * 4 + r][jl] = h[r];
    }
    __syncthreads();
    if (tid < 16) {
        float s = b_out[0];
        for (int j = 0; j < HID; ++j) s += h32[tid][j] * W_out[j];
        out[rowbase + tid] = s;
    }
}

extern "C" void kernel_launch(void* const* d_in, const int* in_sizes, int n_in,
                              void* d_out, int out_size, void* d_ws, size_t ws_size,
                              hipStream_t stream) {
    const float* seq   = (const float*)d_in[0];
    const float* W_ih  = (const float*)d_in[1];
    const float* W_hh  = (const float*)d_in[2];
    const float* b_ih  = (const float*)d_in[3];
    const float* b_hh  = (const float*)d_in[4];
    const float* W_out = (const float*)d_in[5];
    const float* b_out = (const float*)d_in[6];
    float* out = (float*)d_out;

    const int B = in_sizes[0] / (TSTEPS * 4);   // 4096
    lstm_fused<<<dim3(B / 16), dim3(256), 0, stream>>>(
        seq, W_ih, W_hh, b_ih, b_hh, W_out, b_out, out);
}